// Round 10
// baseline (113.849 us; speedup 1.0000x reference)
//
#include <hip/hip_runtime.h>
#include <math.h>

#define B_ 2
#define T_ 512
#define N_ 512
#define H_ 64

typedef _Float16 half8 __attribute__((ext_vector_type(8)));
typedef __attribute__((ext_vector_type(4))) float floatx4;

__device__ inline half8 habs8(half8 v) {
    union { half8 h; unsigned u[4]; } x; x.h = v;
    x.u[0] &= 0x7fff7fffu; x.u[1] &= 0x7fff7fffu;
    x.u[2] &= 0x7fff7fffu; x.u[3] &= 0x7fff7fffu;
    return x.h;
}

// ---------------------------------------------------------------------------
// Kernel 1 (fused node): 64-thread blocks, grid 2176.
//   blk 0..1023    : per-(b,n) dyn context (direct strided reads, 64-wide
//                    butterfly reduce, no LDS) + node MLP (shuffle-based,
//                    R6-proven) -> nrh (f16), P, Qp
//   blk 1024..2047 : prior adjacency table, 4 entries/thread (float4 store)
//   blk 2048..2175 : W3[128:256] f16 pack in MFMA fragment order
// ---------------------------------------------------------------------------
__global__ __launch_bounds__(64) void node_kernel(
        const float* __restrict__ x, const float* __restrict__ mask,
        const float* __restrict__ sc, const float* __restrict__ coords,
        const float* __restrict__ W1, const float* __restrict__ b1,
        const float* __restrict__ W2, const float* __restrict__ b2,
        const float* __restrict__ W3,
        _Float16* __restrict__ nrh, float* __restrict__ P, float* __restrict__ Qp,
        float* __restrict__ prior, _Float16* __restrict__ W3ph) {
    int blk = blockIdx.x;
    int o = threadIdx.x;          // 0..63

    if (blk < 1024) {
        int b = blk >> 9;
        int n = blk & (N_ - 1);

        // ---- dyn context: lane o handles t = o, o+64, ..., o+448 (ascending)
        float sx = 0.f, sxx = 0.f, cnt = 0.f, msum = 0.f, bv = 0.f, bt = -1.f;
#pragma unroll
        for (int k = 0; k < 8; k++) {
            int t = o + (k << 6);
            int off = (b * T_ + t) * N_ + n;
            float xv = x[off];
            float mv = mask[off];
            float obs = 1.f - mv;
            sx   += xv * obs;
            sxx  += xv * xv * obs;
            cnt  += obs;
            msum += mv;
            if (obs > 0.5f) { bt = (float)t; bv = xv; }
        }
        // 64-wide butterfly: all lanes end with the full reduction
#pragma unroll
        for (int off = 1; off < 64; off <<= 1) {
            sx   += __shfl_xor(sx, off);
            sxx  += __shfl_xor(sxx, off);
            cnt  += __shfl_xor(cnt, off);
            msum += __shfl_xor(msum, off);
            float obt = __shfl_xor(bt, off);
            float obv = __shfl_xor(bv, off);
            if (obt > bt) { bt = obt; bv = obv; }
        }
        float count = fmaxf(cnt, 1.f);
        float mean  = sx / count;
        float var   = (sxx - 2.f * mean * sx + mean * mean * cnt) / count;
        float stdv  = sqrtf(fmaxf(var, 0.f) + 1e-6f);
        float last  = (bt >= 0.f) ? bv : x[b * T_ * N_ + n];   // argmax of zeros -> t=0
        float mr    = msum * (1.f / (float)T_);

        // ---- layer 1: dyn features wave-uniform, sc lane-replicated loads
        float a = b1[o] + mean * W1[o] + stdv * W1[H_ + o] +
                  last * W1[2 * H_ + o] + mr * W1[3 * H_ + o];
#pragma unroll
        for (int c = 0; c < 8; c++)
            a += sc[n * 8 + c] * W1[(4 + c) * H_ + o];
        float h = fmaxf(a, 0.f);

        // ---- layer 2 via shuffle broadcast (R6-proven)
        float a2 = b2[o];
#pragma unroll 16
        for (int k = 0; k < H_; k++)
            a2 += __shfl(h, k) * W2[k * H_ + o];
        float rv = fmaxf(a2, 0.f);
        nrh[(b * N_ + n) * H_ + o] = (_Float16)rv;

        // ---- P, Qp via shuffle broadcast
        float p = 0.f, q = 0.f;
#pragma unroll 16
        for (int k = 0; k < H_; k++) {
            float rk = __shfl(rv, k);
            p += rk * W3[k * H_ + o];
            q += rk * W3[(H_ + k) * H_ + o];
        }
        P[(b * N_ + n) * H_ + o] = p;
        Qp[(b * N_ + n) * H_ + (o & 15) * 4 + (o >> 4)] = q;
    } else if (blk < 2048) {
        // ---- prior table: 4 consecutive entries per thread
        int e = (blk - 1024) * 256 + o * 4;
        int pi = e >> 9;
        int pj = e & (N_ - 1);
        float ci[8];
#pragma unroll
        for (int c = 0; c < 8; c++) ci[c] = coords[pi * 8 + c];
        floatx4 pr;
#pragma unroll
        for (int r = 0; r < 4; r++) {
            int j = pj + r;
            float d2 = 0.f;
#pragma unroll
            for (int c = 0; c < 8; c++) {
                float df = ci[c] - coords[j * 8 + c];
                d2 += df * df;
            }
            float dist = (d2 > 0.f) ? sqrtf(d2) : 0.f;
            pr[r] = (pi == j) ? 0.f : 1.f / (1.f + dist);
        }
        *(floatx4*)(prior + e) = pr;
    } else {
        // ---- W3 pack: W3ph[((s*4+nt)*64+l)*8+t] = f16(W3[(128+s*32+quad*8+t)*64 + nt*16+col])
        int k = (blk - 2048) * 64 + o;    // 0..8191
        int t = k & 7;
        int l = (k >> 3) & 63;
        int f = k >> 9;
        int s = f >> 2, nt = f & 3;
        int quad = l >> 4, col = l & 15;
        W3ph[k] = (_Float16)W3[(128 + s * 32 + quad * 8 + t) * H_ + nt * 16 + col];
    }
}

// ---------------------------------------------------------------------------
// Kernel 2 (MFMA, packed f16) — unchanged from R9 (proven).
// Per (b,i): C[j,o] = [D|M](512x128) @ W3cd(128x64); epilogue +P+Qp+b3, relu,
// dot W4, relu, prior; writes adapt row + degree.
// ---------------------------------------------------------------------------
__global__ __launch_bounds__(256) void pair_mfma_kernel(
        const _Float16* __restrict__ nrh, const float* __restrict__ P,
        const float* __restrict__ Qp, const _Float16* __restrict__ W3ph,
        const float* __restrict__ b3, const float* __restrict__ W4,
        const float* __restrict__ b4, const float* __restrict__ prior,
        float* __restrict__ adapt, float* __restrict__ degree) {
    int blk = blockIdx.x;
    int rb = blk >> 9;
    int i = blk & (N_ - 1);
    int tid = threadIdx.x;
    int w = tid >> 6;
    int l = tid & 63;
    int col = l & 15;
    int quad = l >> 4;

    half8 bf[4][4];
#pragma unroll
    for (int s = 0; s < 4; s++)
#pragma unroll
        for (int nt = 0; nt < 4; nt++)
            bf[s][nt] = *(const half8*)(W3ph + (((s * 4 + nt) * 64 + l) << 3));

    const _Float16* hi_row = nrh + (rb * N_ + i) * H_;
    half8 hiA = *(const half8*)(hi_row + quad * 8);
    half8 hiB = *(const half8*)(hi_row + 32 + quad * 8);

    float pb3[4], w4v[4];
#pragma unroll
    for (int nt = 0; nt < 4; nt++) {
        int o = nt * 16 + col;
        pb3[nt] = P[(rb * N_ + i) * H_ + o] + b3[o];
        w4v[nt] = W4[o];
    }
    float b4s = b4[0];
    const float* prow = prior + i * N_;
    const _Float16* nrb = nrh + (rb * N_) * H_;
    float rsum = 0.f;

    half8 hA, hB;
    {
        const _Float16* p0 = nrb + (w * 128 + col) * H_;
        hA = *(const half8*)(p0 + quad * 8);
        hB = *(const half8*)(p0 + 32 + quad * 8);
    }

#pragma unroll
    for (int mt = 0; mt < 8; mt++) {
        int j0 = w * 128 + mt * 16;

        half8 nA, nB;
        if (mt < 7) {
            const _Float16* pn = nrb + (j0 + 16 + col) * H_;
            nA = *(const half8*)(pn + quad * 8);
            nB = *(const half8*)(pn + 32 + quad * 8);
        }

        floatx4 pv = *(const floatx4*)(prow + j0 + quad * 4);
        floatx4 qv[4];
#pragma unroll
        for (int r = 0; r < 4; r++)
            qv[r] = *(const floatx4*)(Qp + (rb * N_ + j0 + quad * 4 + r) * H_ + col * 4);

        half8 dA = habs8(hiA - hA);
        half8 dB = habs8(hiB - hB);
        half8 mA = hiA * hA;
        half8 mB = hiB * hB;

        floatx4 acc[4];
#pragma unroll
        for (int nt = 0; nt < 4; nt++) acc[nt] = (floatx4){0.f, 0.f, 0.f, 0.f};
#pragma unroll
        for (int nt = 0; nt < 4; nt++) {
            acc[nt] = __builtin_amdgcn_mfma_f32_16x16x32_f16(dA, bf[0][nt], acc[nt], 0, 0, 0);
            acc[nt] = __builtin_amdgcn_mfma_f32_16x16x32_f16(dB, bf[1][nt], acc[nt], 0, 0, 0);
            acc[nt] = __builtin_amdgcn_mfma_f32_16x16x32_f16(mA, bf[2][nt], acc[nt], 0, 0, 0);
            acc[nt] = __builtin_amdgcn_mfma_f32_16x16x32_f16(mB, bf[3][nt], acc[nt], 0, 0, 0);
        }

        float ed[4];
#pragma unroll
        for (int r = 0; r < 4; r++) {
            int j = j0 + quad * 4 + r;
            float p = 0.f;
#pragma unroll
            for (int nt = 0; nt < 4; nt++)
                p += fmaxf(acc[nt][r] + pb3[nt] + qv[r][nt], 0.f) * w4v[nt];
            p += __shfl_xor(p, 1);
            p += __shfl_xor(p, 2);
            p += __shfl_xor(p, 4);
            p += __shfl_xor(p, 8);
            float edge = fmaxf(p + b4s, 0.f);
            float ad = (j == i) ? 1.0f : edge * pv[r];
            ed[r] = ad;
            rsum += ad;
        }
        if (col == 0) {
            *(floatx4*)&adapt[(size_t)(rb * N_ + i) * N_ + j0 + quad * 4] =
                (floatx4){ed[0], ed[1], ed[2], ed[3]};
        }
        if (mt < 7) { hA = nA; hB = nB; }
    }

    rsum += __shfl_xor(rsum, 16);
    rsum += __shfl_xor(rsum, 32);
    __shared__ float sRow[4];
    if (l == 0) sRow[w] = rsum;
    __syncthreads();
    if (tid == 0) degree[rb * N_ + i] = sRow[0] + sRow[1] + sRow[2] + sRow[3];
}

// ---------------------------------------------------------------------------
// Kernel 3: symmetric normalization out = D^-1/2 A D^-1/2 (float4) — unchanged
// ---------------------------------------------------------------------------
__global__ void norm_kernel(const float* __restrict__ adapt, const float* __restrict__ deg,
                            float* __restrict__ out) {
    int idx = blockIdx.x * 256 + threadIdx.x;
    int b = idx >> 16;
    int r = (idx >> 7) & (N_ - 1);
    int c4 = (idx & 127) << 2;
    float dr = rsqrtf(fmaxf(deg[b * N_ + r], 1e-6f));
    floatx4 a = *(const floatx4*)(adapt + ((size_t)idx << 2));
    floatx4 o;
#pragma unroll
    for (int k = 0; k < 4; k++)
        o[k] = dr * a[k] * rsqrtf(fmaxf(deg[b * N_ + c4 + k], 1e-6f));
    *(floatx4*)(out + ((size_t)idx << 2)) = o;
}

extern "C" void kernel_launch(void* const* d_in, const int* in_sizes, int n_in,
                              void* d_out, int out_size, void* d_ws, size_t ws_size,
                              hipStream_t stream) {
    const float* x      = (const float*)d_in[0];
    const float* mask   = (const float*)d_in[1];
    const float* sc     = (const float*)d_in[2];
    const float* coords = (const float*)d_in[3];
    const float* W1 = (const float*)d_in[4];
    const float* b1 = (const float*)d_in[5];
    const float* W2 = (const float*)d_in[6];
    const float* b2 = (const float*)d_in[7];
    const float* W3 = (const float*)d_in[8];
    const float* b3 = (const float*)d_in[9];
    const float* W4 = (const float*)d_in[10];
    const float* b4 = (const float*)d_in[11];
    float* out = (float*)d_out;

    float* wsp = (float*)d_ws;
    float* P       = wsp;                            // 65536 floats
    float* Qp      = wsp + 65536;                    // 65536
    float* prior   = wsp + 131072;                   // 262144
    _Float16* nrh  = (_Float16*)(wsp + 393216);      // 65536 halves (32768 floats)
    _Float16* W3ph = (_Float16*)(wsp + 425984);      // 8192 halves (4096 floats)
    float* deg     = wsp + 430080;                   // 1024
    float* adapt   = wsp + 431104;                   // 524288

    node_kernel<<<2176, 64, 0, stream>>>(x, mask, sc, coords, W1, b1, W2, b2, W3,
                                         nrh, P, Qp, prior, W3ph);
    pair_mfma_kernel<<<B_ * N_, 256, 0, stream>>>(nrh, P, Qp, W3ph, b3, W4, b4, prior, adapt, deg);
    norm_kernel<<<512, 256, 0, stream>>>(adapt, deg, out);
}